// Round 3
// baseline (620.697 us; speedup 1.0000x reference)
//
#include <hip/hip_runtime.h>
#include <stdint.h>

#define NB 32      // batch
#define NSEQ 320   // tokens
#define CDIM 768
#define NH 12
#define HD 64
#define MLPH 3072
#define MROWS (NB*NSEQ)   // 10240

typedef __attribute__((ext_vector_type(8))) short v8s;
typedef __attribute__((ext_vector_type(4))) float v4f;

__device__ __forceinline__ unsigned short f2b(float f){
  unsigned int u = __float_as_uint(f);
  u += 0x7fffu + ((u >> 16) & 1u);
  return (unsigned short)(u >> 16);
}
__device__ __forceinline__ float b2f(unsigned short h){
  return __uint_as_float(((unsigned int)h) << 16);
}
__device__ __forceinline__ void glds16(const unsigned short* g, unsigned short* l){
  __builtin_amdgcn_global_load_lds(
      (const __attribute__((address_space(1))) void*)g,
      (__attribute__((address_space(3))) void*)l, 16, 0, 0);
}

// ---------------- weight cast + transpose: W (K,N) f32 -> Wt (N,K) bf16 -------
__global__ __launch_bounds__(256)
void castT(const float* __restrict__ W, unsigned short* __restrict__ Wt, int K, int N){
  __shared__ float tile[32][33];
  const int k0 = blockIdx.x * 32, n0 = blockIdx.y * 32;
  const int tx = threadIdx.x & 31, ty = threadIdx.x >> 5;   // ty 0..7
  #pragma unroll
  for (int i = 0; i < 32; i += 8)
    tile[ty + i][tx] = W[(size_t)(k0 + ty + i) * N + n0 + tx];
  __syncthreads();
  #pragma unroll
  for (int i = 0; i < 32; i += 8)
    Wt[(size_t)(n0 + ty + i) * K + k0 + tx] = f2b(tile[tx][ty + i]);
}

// ---------------- row LayerNorm (f32 in) -> bf16 out --------------------------
__global__ __launch_bounds__(192)
void ln_to_bf16(const float* __restrict__ x, const float* __restrict__ g,
                const float* __restrict__ be, unsigned short* __restrict__ out){
  const int row = blockIdx.x;
  const int t = threadIdx.x, w = t >> 6, l = t & 63;
  const float4 v = *(const float4*)(x + (size_t)row * CDIM + t * 4);
  float s  = v.x + v.y + v.z + v.w;
  float s2 = v.x*v.x + v.y*v.y + v.z*v.z + v.w*v.w;
  __shared__ float r1[3], r2[3];
  #pragma unroll
  for (int d = 1; d < 64; d <<= 1){ s += __shfl_xor(s, d, 64); s2 += __shfl_xor(s2, d, 64); }
  if (l == 0){ r1[w] = s; r2[w] = s2; }
  __syncthreads();
  const float S = r1[0] + r1[1] + r1[2];
  const float S2 = r2[0] + r2[1] + r2[2];
  const float mean = S * (1.0f / CDIM);
  const float var  = S2 * (1.0f / CDIM) - mean * mean;
  const float rs = rsqrtf(var + 1e-5f);
  const float4 gg = *(const float4*)(g + t * 4);
  const float4 bb = *(const float4*)(be + t * 4);
  ushort4 o;
  o.x = f2b((v.x - mean) * rs * gg.x + bb.x);
  o.y = f2b((v.y - mean) * rs * gg.y + bb.y);
  o.z = f2b((v.z - mean) * rs * gg.z + bb.z);
  o.w = f2b((v.w - mean) * rs * gg.w + bb.w);
  *(ushort4*)(out + (size_t)row * CDIM + t * 4) = o;
}

// ============ 8-phase 256-row-tile bf16 MFMA GEMM (T3+T4+T2+T5) ==============
// C = A(M,K) @ Bt(N,K)^T.  BM=256, BN=NF*64, BK=64, 512 thr = 8 waves (2M x 4N).
// LDS double-buffered; XOR-swizzle (row&7)<<4 on byte offset, applied as an
// involution: pre-swizzled global_load_lds source + swizzled ds_read address.
// One counted vmcnt per K-tile (8 for NF=4, 6 for NF=2) -- never 0 mid-loop.
#define BARX() do { asm volatile("" ::: "memory"); __builtin_amdgcn_s_barrier(); asm volatile("" ::: "memory"); } while(0)

#define READA(BUF, MH) do { \
  _Pragma("unroll") \
  for (int mi = 0; mi < 4; ++mi){ \
    const int row_ = wm*128 + (MH)*64 + mi*16 + (l & 15); \
    _Pragma("unroll") \
    for (int kk = 0; kk < 2; ++kk) \
      af[mi][kk] = *(const v8s*)((const char*)(BUF) + row_*128 + ((kk*64 + ((l>>4)<<4)) ^ ((l&7)<<4))); \
  } } while(0)

#define READB(BUF, NH, BR) do { \
  _Pragma("unroll") \
  for (int nf = 0; nf < NHF; ++nf){ \
    const int row_ = wn*(NF*16) + (NH)*(NHF*16) + nf*16 + (l & 15); \
    _Pragma("unroll") \
    for (int kk = 0; kk < 2; ++kk) \
      BR[nf][kk] = *(const v8s*)((const char*)(BUF) + row_*128 + ((kk*64 + ((l>>4)<<4)) ^ ((l&7)<<4))); \
  } } while(0)

#define QUADX(MH, NH, BR) do { \
  __builtin_amdgcn_s_setprio(1); \
  _Pragma("unroll") \
  for (int mi = 0; mi < 4; ++mi) \
    _Pragma("unroll") \
    for (int nf = 0; nf < NHF; ++nf){ \
      v4f c_ = acc[(MH)*4+mi][(NH)*NHF+nf]; \
      c_ = __builtin_amdgcn_mfma_f32_16x16x32_bf16(af[mi][0], BR[nf][0], c_, 0, 0, 0); \
      c_ = __builtin_amdgcn_mfma_f32_16x16x32_bf16(af[mi][1], BR[nf][1], c_, 0, 0, 0); \
      acc[(MH)*4+mi][(NH)*NHF+nf] = c_; \
    } \
  __builtin_amdgcn_s_setprio(0); \
} while(0)

template<int NF, bool BIAS, bool RES, bool GELU, bool WB, bool WF>
__global__ __launch_bounds__(512, 2)
void gemm8p(const unsigned short* __restrict__ A, const unsigned short* __restrict__ Bt,
            int N, int K,
            const float* __restrict__ bias, const float* __restrict__ res,
            unsigned short* __restrict__ outb, float* __restrict__ outf){
  constexpr int BN  = NF * 64;
  constexpr int NHF = NF / 2;
  __shared__ __align__(16) unsigned short lds[2*256*64 + 2*BN*64];
  unsigned short* const A0 = lds;
  unsigned short* const A1 = lds + 256*64;
  unsigned short* const B0 = lds + 2*256*64;
  unsigned short* const B1 = lds + 2*256*64 + BN*64;

  const int tid = threadIdx.x;
  const int w = tid >> 6, l = tid & 63;
  const int wm = w >> 2, wn = w & 3;
  const int bm = blockIdx.x, bn = blockIdx.y;
  const int nt = K >> 6;

  const int swz = ((l & 7) ^ (l >> 3)) << 3;   // pre-swizzled src (elems)
  const int lr8 = l >> 3;

  v4f acc[8][NF];
  #pragma unroll
  for (int i = 0; i < 8; ++i)
    #pragma unroll
    for (int j = 0; j < NF; ++j) acc[i][j] = v4f{0.f, 0.f, 0.f, 0.f};

  v8s af[4][2], b0r[NHF][2], b1r[NHF][2];

  auto stageA = [&](unsigned short* buf, int h, int kt){
    #pragma unroll
    for (int i = 0; i < 2; ++i){
      const int lr = i*128 + h*64 + w*8;       // wave-uniform LDS row base
      glds16(A + (size_t)(bm*256 + lr + lr8) * K + kt*64 + swz, buf + lr*64);
    }
  };
  auto stageB = [&](unsigned short* buf, int nh, int kt){
    if constexpr (NF == 4){
      #pragma unroll
      for (int i = 0; i < 2; ++i){
        const int lr = (i*2 + (w>>2))*64 + nh*32 + (w&3)*8;
        glds16(Bt + (size_t)(bn*BN + lr + lr8) * K + kt*64 + swz, buf + lr*64);
      }
    } else {
      const int lr = (w>>1)*32 + nh*16 + (w&1)*8;
      glds16(Bt + (size_t)(bn*BN + lr + lr8) * K + kt*64 + swz, buf + lr*64);
    }
  };

  // prologue: tiles 0 and 1, group order fixed for the vmcnt queue arithmetic
  stageA(A0, 0, 0); stageB(B0, 0, 0); stageB(B0, 1, 0); stageA(A0, 1, 0);
  stageA(A1, 0, 1); stageB(B1, 0, 1); stageB(B1, 1, 1); stageA(A1, 1, 1);
  if constexpr (NF == 4) asm volatile("s_waitcnt vmcnt(8)" ::: "memory");
  else                   asm volatile("s_waitcnt vmcnt(6)" ::: "memory");
  __builtin_amdgcn_s_barrier();

  #pragma unroll 1
  for (int t = 0; t < nt; ++t){
    unsigned short* const Ac = (t & 1) ? A1 : A0;
    unsigned short* const Bc = (t & 1) ? B1 : B0;
    // P1: quadrant (mh0 x nh0)
    READA(Ac, 0); READB(Bc, 0, b0r);
    BARX(); QUADX(0, 0, b0r); BARX();
    // P2: (mh0 x nh1); prefetch A-mh0(t+2) into region consumed in P1
    READB(Bc, 1, b1r);
    if (t + 2 < nt) stageA(Ac, 0, t + 2);
    BARX(); QUADX(0, 1, b1r); BARX();
    // P3: (mh1 x nh1); prefetch B-nh0(t+2)
    READA(Ac, 1);
    if (t + 2 < nt) stageB(Bc, 0, t + 2);
    BARX(); QUADX(1, 1, b1r); BARX();
    // P4: (mh1 x nh0); prefetch B-nh1(t+2), A-mh1(t+2); counted wait for tile t+1
    if (t + 2 < nt){
      stageB(Bc, 1, t + 2); stageA(Ac, 1, t + 2);
      if constexpr (NF == 4) asm volatile("s_waitcnt vmcnt(8)" ::: "memory");
      else                   asm volatile("s_waitcnt vmcnt(6)" ::: "memory");
    } else {
      asm volatile("s_waitcnt vmcnt(0)" ::: "memory");
    }
    BARX(); QUADX(1, 0, b0r); BARX();
  }

  const int r0 = bm*256 + wm*128 + ((l >> 4) << 2);
  const int c0 = bn*BN + wn*(NF*16) + (l & 15);
  #pragma unroll
  for (int mg = 0; mg < 8; ++mg){
    const int rowoff = (mg >> 2)*64 + (mg & 3)*16;
    #pragma unroll
    for (int rr = 0; rr < 4; ++rr){
      const int row = r0 + rowoff + rr;
      #pragma unroll
      for (int ng = 0; ng < NF; ++ng){
        const int col = c0 + ng*16;
        float c = acc[mg][ng][rr];
        if (BIAS) c += bias[col];
        if (RES)  c += res[(size_t)row * N + col];
        if (GELU) c = 0.5f * c * (1.0f + erff(c * 0.70710678118f));
        if (WB) outb[(size_t)row * N + col] = f2b(c);
        if (WF) outf[(size_t)row * N + col] = c;
      }
    }
  }
}
#undef READA
#undef READB
#undef QUADX

// ---------------- attention: per (b,h,qtile of 64 rows) -----------------------
// qkv layout: [(b*320+n)*2304 + s*768 + h*64 + d], bf16
__global__ __launch_bounds__(256, 2)
void attn_kernel(const unsigned short* __restrict__ qkv,
                 unsigned short* __restrict__ ctx,
                 float* __restrict__ wparts){
  __shared__ __align__(16) unsigned short Qs[64 * 72];
  __shared__ __align__(16) unsigned short KV[64 * 72];   // K tile, then V^T tile
  __shared__ __align__(16) unsigned short Ps[64 * 328];
  const int t = threadIdx.x;
  const int w = t >> 6, l = t & 63;
  const int bid = blockIdx.x;
  const int qt = bid % 5;
  const int h  = (bid / 5) % NH;
  const int b  = bid / (5 * NH);
  const size_t base = (size_t)b * NSEQ * 2304 + h * 64;

  { // stage Q (64 x 64)
    const int r = t >> 3, seg = t & 7;
    #pragma unroll
    for (int i = 0; i < 2; ++i){
      const int r2 = r + 32 * i;
      const unsigned short* src = qkv + base + (size_t)(qt * 64 + r2) * 2304 + seg * 8;
      *(uint4*)&Qs[r2 * 72 + seg * 8] = *(const uint4*)src;
    }
  }
  __syncthreads();
  const int qr = 16 * w + (l & 15);
  const v8s aq0 = *(const v8s*)&Qs[qr * 72 + ((l >> 4) << 3)];
  const v8s aq1 = *(const v8s*)&Qs[qr * 72 + 32 + ((l >> 4) << 3)];

  v4f sacc[20] = {};
  for (int kt = 0; kt < 5; ++kt){
    __syncthreads();
    { // stage K tile
      const int r = t >> 3, seg = t & 7;
      #pragma unroll
      for (int i = 0; i < 2; ++i){
        const int r2 = r + 32 * i;
        const unsigned short* src = qkv + base + 768 + (size_t)(kt * 64 + r2) * 2304 + seg * 8;
        *(uint4*)&KV[r2 * 72 + seg * 8] = *(const uint4*)src;
      }
    }
    __syncthreads();
    #pragma unroll
    for (int f = 0; f < 4; ++f){
      const int kr = 16 * f + (l & 15);
      const v8s b0 = *(const v8s*)&KV[kr * 72 + ((l >> 4) << 3)];
      const v8s b1 = *(const v8s*)&KV[kr * 72 + 32 + ((l >> 4) << 3)];
      sacc[kt * 4 + f] = __builtin_amdgcn_mfma_f32_16x16x32_bf16(aq0, b0, sacc[kt * 4 + f], 0, 0, 0);
      sacc[kt * 4 + f] = __builtin_amdgcn_mfma_f32_16x16x32_bf16(aq1, b1, sacc[kt * 4 + f], 0, 0, 0);
    }
  }

  // wave-parallel softmax; rows live in 16-lane groups (xor 1,2,4,8 stays in-group)
  const float scale = 0.125f;
  #pragma unroll
  for (int r = 0; r < 4; ++r){
    float m = -1e30f;
    #pragma unroll
    for (int f = 0; f < 20; ++f) m = fmaxf(m, sacc[f][r]);
    #pragma unroll
    for (int d = 1; d < 16; d <<= 1) m = fmaxf(m, __shfl_xor(m, d, 64));
    const float Ms = m * scale;
    float sum = 0.f;
    #pragma unroll
    for (int f = 0; f < 20; ++f){ float p = expf(sacc[f][r] * scale - Ms); sacc[f][r] = p; sum += p; }
    #pragma unroll
    for (int d = 1; d < 16; d <<= 1) sum += __shfl_xor(sum, d, 64);
    const float inv = 1.0f / sum;
    const int rowq = 16 * w + ((l >> 4) << 2) + r;
    #pragma unroll
    for (int f = 0; f < 20; ++f)
      Ps[rowq * 328 + f * 16 + (l & 15)] = f2b(sacc[f][r] * inv);
    if (qt == 0){
      #pragma unroll
      for (int f = 4; f < 20; ++f)
        wparts[(((size_t)b * NH + h) * 64 + rowq) * 256 + (f - 4) * 16 + (l & 15)] = sacc[f][r] * inv;
    }
  }

  // P @ V
  v4f cacc[4] = {};
  for (int kt = 0; kt < 5; ++kt){
    __syncthreads();
    { // stage V^T tile: KV[d*72 + m] = V[m][d]
      const int m = t & 31, d0 = (t >> 5) * 8;
      #pragma unroll
      for (int i = 0; i < 2; ++i){
        const int m2 = m + 32 * i;
        const unsigned short* src = qkv + base + 1536 + (size_t)(kt * 64 + m2) * 2304 + d0;
        uint4 dv = *(const uint4*)src;
        const unsigned short* e = (const unsigned short*)&dv;
        #pragma unroll
        for (int jj = 0; jj < 8; ++jj) KV[(d0 + jj) * 72 + m2] = e[jj];
      }
    }
    __syncthreads();
    const int pr = 16 * w + (l & 15);
    const v8s pa0 = *(const v8s*)&Ps[pr * 328 + kt * 64 + ((l >> 4) << 3)];
    const v8s pa1 = *(const v8s*)&Ps[pr * 328 + kt * 64 + 32 + ((l >> 4) << 3)];
    #pragma unroll
    for (int f = 0; f < 4; ++f){
      const int vc = 16 * f + (l & 15);
      const v8s bv0 = *(const v8s*)&KV[vc * 72 + ((l >> 4) << 3)];
      const v8s bv1 = *(const v8s*)&KV[vc * 72 + 32 + ((l >> 4) << 3)];
      cacc[f] = __builtin_amdgcn_mfma_f32_16x16x32_bf16(pa0, bv0, cacc[f], 0, 0, 0);
      cacc[f] = __builtin_amdgcn_mfma_f32_16x16x32_bf16(pa1, bv1, cacc[f], 0, 0, 0);
    }
  }
  #pragma unroll
  for (int f = 0; f < 4; ++f)
    #pragma unroll
    for (int rr = 0; rr < 4; ++rr){
      const int rowq = 16 * w + ((l >> 4) << 2) + rr;
      const int col = 16 * f + (l & 15);
      ctx[(size_t)(b * NSEQ + qt * 64 + rowq) * CDIM + h * 64 + col] = f2b(cacc[f][rr]);
    }
}

// ---------------- w_ts: sum over heads /H then softmax over 256; bf16 x2 ------
__global__ __launch_bounds__(256)
void wts_softmax(const float* __restrict__ wparts,
                 unsigned short* __restrict__ wtsb,
                 unsigned short* __restrict__ wtsbT){
  const int row = blockIdx.x;            // b*64 + n
  const int b = row >> 6, n = row & 63;
  const int j = threadIdx.x;
  const int w = j >> 6, l = j & 63;
  float s = 0.f;
  #pragma unroll
  for (int hh = 0; hh < NH; ++hh)
    s += wparts[(((size_t)b * NH + hh) * 64 + n) * 256 + j];
  s *= (1.0f / NH);
  __shared__ float red[8];
  float m = s;
  #pragma unroll
  for (int d = 1; d < 64; d <<= 1) m = fmaxf(m, __shfl_xor(m, d, 64));
  if (l == 0) red[w] = m;
  __syncthreads();
  m = fmaxf(fmaxf(red[0], red[1]), fmaxf(red[2], red[3]));
  const float e = expf(s - m);
  float sm = e;
  #pragma unroll
  for (int d = 1; d < 64; d <<= 1) sm += __shfl_xor(sm, d, 64);
  if (l == 0) red[4 + w] = sm;
  __syncthreads();
  const float tot = red[4] + red[5] + red[6] + red[7];
  const unsigned short p = f2b(e / tot);
  wtsb [((size_t)b * 64 + n) * 256 + j] = p;
  wtsbT[((size_t)b * 256 + j) * 64 + n] = p;
}

// ---------------- support transpose: (b,320,768) -> (b,768,320) bf16 ----------
__global__ __launch_bounds__(256)
void transT(const unsigned short* __restrict__ in, unsigned short* __restrict__ out){
  __shared__ unsigned short tile[64][65];   // [c][n]
  const int c0 = blockIdx.x * 64, n0 = blockIdx.y * 64, b = blockIdx.z;
  const int tx = threadIdx.x & 31, ty = threadIdx.x >> 5;  // ty 0..7
  const unsigned short* ib = in + (size_t)b * NSEQ * CDIM;
  unsigned short* ob = out + (size_t)b * CDIM * NSEQ;
  #pragma unroll
  for (int i = 0; i < 64; i += 8){
    const unsigned int v = *(const unsigned int*)&ib[(size_t)(n0 + ty + i) * CDIM + c0 + tx * 2];
    tile[tx * 2][ty + i]     = (unsigned short)(v & 0xffff);
    tile[tx * 2 + 1][ty + i] = (unsigned short)(v >> 16);
  }
  __syncthreads();
  #pragma unroll
  for (int i = 0; i < 64; i += 8){
    const int c = ty + i;
    const unsigned int v = (unsigned int)tile[c][tx * 2] | ((unsigned int)tile[c][tx * 2 + 1] << 16);
    *(unsigned int*)&ob[(size_t)(c0 + c) * NSEQ + n0 + tx * 2] = v;
  }
}

// ---------------- graph matmul via MFMA ---------------------------------------
template<int KC, int SH2>   // KC = K-chunk, SH2 = log2(KC*2)
__global__ __launch_bounds__(256, 2)
void graph_gemm(const unsigned short* __restrict__ A, int KTOT,
                const unsigned short* __restrict__ supT, int koff,
                float* __restrict__ y, int rowoff){
  __shared__ __align__(16) unsigned short As[64 * KC];
  __shared__ __align__(16) unsigned short Bs[128 * KC];
  const int t = threadIdx.x, w = t >> 6, l = t & 63;
  const int mt = blockIdx.x, ct = blockIdx.y, b = blockIdx.z;
  const char* Ab = (const char*)(A + (size_t)b * 16384 + (size_t)mt * 64 * KTOT);
  const char* Bb = (const char*)(supT + (size_t)b * CDIM * NSEQ);
  v4f acc[4][2] = {};

  const int nch = KTOT / KC;
  for (int ch = 0; ch < nch; ++ch){
    if (ch) __syncthreads();
    const int kbase = (koff + ch * KC) * 2;   // byte offset into supT row
    #pragma unroll
    for (int i = 0; i < KC / 32; ++i){        // stage A chunk (swizzled)
      const int gi = w * (KC / 32) + i;
      const int X = gi * 1024 + l * 16;
      const int c = X >> SH2;
      const int k2 = (X & (KC * 2 - 1)) ^ ((c & 7) << 4);
      glds16((const unsigned short*)(Ab + (size_t)c * (KTOT * 2) + ch * KC * 2 + k2),
             As + (gi * 512));
    }
    #pragma unroll
    for (int i = 0; i < KC / 16; ++i){        // stage B chunk (swizzled)
      const int gi = w * (KC / 16) + i;
      const int X = gi * 1024 + l * 16;
      const int c = X >> SH2;
      const int k2 = (X & (KC * 2 - 1)) ^ ((c & 7) << 4);
      glds16((const unsigned short*)(Bb + (size_t)(ct * 128 + c) * (NSEQ * 2) + kbase + k2),
             Bs + (gi * 512));
    }
    __syncthreads();
    #pragma unroll
    for (int ks = 0; ks < KC / 32; ++ks){
      const int kbyte = ks * 64 + ((l >> 4) << 4);
      v8s af[4], bf2[2];
      #pragma unroll
      for (int mi = 0; mi < 4; ++mi){
        const int r = mi * 16 + (l & 15);
        af[mi] = *(const v8s*)((const char*)As + (r << SH2) + (kbyte ^ ((r & 7) << 4)));
      }
      #pragma unroll
      for (int ni = 0; ni < 2; ++ni){
        const int rb = w * 32 + ni * 16 + (l & 15);
        bf2[ni] = *(const v8s*)((const char*)Bs + (rb << SH2) + (kbyte ^ ((rb & 7) << 4)));
      }
      #pragma unroll
      for (int mi = 0; mi < 4; ++mi)
        #pragma unroll
        for (int ni = 0; ni < 2; ++ni)
          acc[mi][ni] = __builtin_amdgcn_mfma_f32_16x16x32_bf16(af[mi], bf2[ni], acc[mi][ni], 0, 0, 0);
    }
  }

  const int r0 = rowoff + mt * 64 + ((l >> 4) << 2);
  const int c0 = ct * 128 + w * 32 + (l & 15);
  #pragma unroll
  for (int mi = 0; mi < 4; ++mi)
    #pragma unroll
    for (int ni = 0; ni < 2; ++ni)
      #pragma unroll
      for (int rr = 0; rr < 4; ++rr)
        y[((size_t)b * NSEQ + r0 + mi * 16 + rr) * CDIM + c0 + ni * 16] = acc[mi][ni][rr];
}

// ---------------- final: out = y + LN(y) --------------------------------------
__global__ __launch_bounds__(192)
void ln_final(const float* __restrict__ y, const float* __restrict__ g3,
              const float* __restrict__ b3, float* __restrict__ out){
  const int row = blockIdx.x;
  const int t = threadIdx.x, w = t >> 6, l = t & 63;
  const float4 v = *(const float4*)(y + (size_t)row * CDIM + t * 4);
  float s  = v.x + v.y + v.z + v.w;
  float s2 = v.x*v.x + v.y*v.y + v.z*v.z + v.w*v.w;
  __shared__ float r1[3], r2[3];
  #pragma unroll
  for (int d = 1; d < 64; d <<= 1){ s += __shfl_xor(s, d, 64); s2 += __shfl_xor(s2, d, 64); }
  if (l == 0){ r1[w] = s; r2[w] = s2; }
  __syncthreads();
  const float S = r1[0] + r1[1] + r1[2];
  const float S2 = r2[0] + r2[1] + r2[2];
  const float mean = S * (1.0f / CDIM);
  const float var  = S2 * (1.0f / CDIM) - mean * mean;
  const float rs = rsqrtf(var + 1e-5f);
  const float4 gg = *(const float4*)(g3 + t * 4);
  const float4 bb = *(const float4*)(b3 + t * 4);
  float4 o;
  o.x = v.x + (v.x - mean) * rs * gg.x + bb.x;
  o.y = v.y + (v.y - mean) * rs * gg.y + bb.y;
  o.z = v.z + (v.z - mean) * rs * gg.z + bb.z;
  o.w = v.w + (v.w - mean) * rs * gg.w + bb.w;
  *(float4*)(out + (size_t)row * CDIM + t * 4) = o;
}

extern "C" void kernel_launch(void* const* d_in, const int* in_sizes, int n_in,
                              void* d_out, int out_size, void* d_ws, size_t ws_size,
                              hipStream_t stream){
  (void)in_sizes; (void)n_in; (void)out_size; (void)ws_size;
  const float* x    = (const float*)d_in[0];
  const float* g1   = (const float*)d_in[3];
  const float* b1   = (const float*)d_in[4];
  const float* Wqkv = (const float*)d_in[5];
  const float* Wproj= (const float*)d_in[6];
  const float* bproj= (const float*)d_in[7];
  const float* g2   = (const float*)d_in[8];
  const float* b2   = (const float*)d_in[9];
  const float* W1   = (const float*)d_in[10];
  const float* bm1  = (const float*)d_in[11];
  const float* W2   = (const float*)d_in[12];
  const float* bm2  = (const float*)d_in[13];
  const float* Wg   = (const float*)d_in[14];
  const float* bg   = (const float*)d_in[15];
  const float* g3   = (const float*)d_in[16];
  const float* b3   = (const float*)d_in[17];
  float* out = (float*)d_out;
  char* ws = (char*)d_ws;

  // workspace layout (bytes); aliases are time-disjoint
  unsigned short* wqkvT = (unsigned short*)(ws + 0);          // 3,538,944
  unsigned short* wprojT= (unsigned short*)(ws + 3538944);    // 1,179,648
  unsigned short* w1T   = (unsigned short*)(ws + 4718592);    // 4,718,592
  unsigned short* w2T   = (unsigned short*)(ws + 9437184);    // 4,718,592
  unsigned short* wgT   = (unsigned short*)(ws + 14155776);   // 1,179,648
  unsigned short* xn1   = (unsigned short*)(ws + 15335424);   // 15,728,640
  unsigned short* qkvb  = (unsigned short*)(ws + 31064064);   // 47,185,920
  unsigned short* hb    = (unsigned short*)(ws + 15335424);   // aliases xn1+qkv
  unsigned short* supT  = (unsigned short*)(ws + 15335424);   // aliases hb (dead after MLP2)
  unsigned short* ctxb  = (unsigned short*)(ws + 78249984);   // 15,728,640
  unsigned short* x2b   = (unsigned short*)(ws + 78249984);   // aliases ctx
  unsigned short* xn2   = (unsigned short*)(ws + 93978624);   // 15,728,640
  unsigned short* supb  = (unsigned short*)(ws + 93978624);   // aliases xn2
  float*          x1    = (float*)(ws + 109707264);           // 31,457,280
  float*          wparts= (float*)(ws + 109707264);           // aliases x1
  float*          yb    = (float*)(ws + 109707264);           // aliases x1 (dead after MLP2)
  unsigned short* wtsb  = (unsigned short*)(ws + 141164544);  // 1,048,576
  unsigned short* wtsbT = (unsigned short*)(ws + 142213120);  // 1,048,576

  // 1) weights -> bf16, transposed to (N,K)
  castT<<<dim3(CDIM/32, 2304/32), 256, 0, stream>>>(Wqkv, wqkvT, CDIM, 2304);
  castT<<<dim3(CDIM/32, CDIM/32), 256, 0, stream>>>(Wproj, wprojT, CDIM, CDIM);
  castT<<<dim3(CDIM/32, MLPH/32), 256, 0, stream>>>(W1, w1T, CDIM, MLPH);
  castT<<<dim3(MLPH/32, CDIM/32), 256, 0, stream>>>(W2, w2T, MLPH, CDIM);
  castT<<<dim3(CDIM/32, CDIM/32), 256, 0, stream>>>(Wg, wgT, CDIM, CDIM);

  // 2) LN1 -> bf16
  ln_to_bf16<<<MROWS, 192, 0, stream>>>(x, g1, b1, xn1);

  // 3) QKV GEMM (no bias): M=10240, N=2304, K=768
  gemm8p<2,false,false,false,true,false><<<dim3(40, 18), 512, 0, stream>>>(
      xn1, wqkvT, 2304, CDIM, nullptr, nullptr, qkvb, nullptr);

  // 4) attention (also emits per-head prob slices for w_ts)
  attn_kernel<<<NB * NH * 5, 256, 0, stream>>>(qkvb, ctxb, wparts);

  // 5) w_ts = softmax(sum_h attn[:,:64,64:]/H), bf16 in both orientations
  wts_softmax<<<NB * 64, 256, 0, stream>>>(wparts, wtsb, wtsbT);

  // 6) proj + bias + residual(x) -> x1 (f32)
  gemm8p<2,true,true,false,false,true><<<dim3(40, 6), 512, 0, stream>>>(
      ctxb, wprojT, CDIM, CDIM, bproj, x, nullptr, x1);

  // 7) LN2 -> bf16
  ln_to_bf16<<<MROWS, 192, 0, stream>>>(x1, g2, b2, xn2);

  // 8) MLP1 + bias + exact GELU -> h (bf16): N=3072, K=768
  gemm8p<4,true,false,true,true,false><<<dim3(40, 12), 512, 0, stream>>>(
      xn2, w1T, MLPH, CDIM, bm1, nullptr, hb, nullptr);

  // 9) MLP2 + bias + residual(x1) -> x2 (bf16): N=768, K=3072
  gemm8p<2,true,true,false,true,false><<<dim3(40, 6), 512, 0, stream>>>(
      hb, w2T, CDIM, MLPH, bm2, x1, x2b, nullptr);

  // 10) support = x2 @ Wg + bg (bf16)
  gemm8p<2,true,false,false,true,false><<<dim3(40, 6), 512, 0, stream>>>(
      x2b, wgT, CDIM, CDIM, bg, nullptr, supb, nullptr);

  // 11) supT = transpose(support) per batch
  transT<<<dim3(CDIM/64, NSEQ/64, NB), 256, 0, stream>>>(supb, supT);

  // 12) y = adj @ support via two batched MFMA GEMMs
  graph_gemm<128, 8><<<dim3(1, 6, NB), 256, 0, stream>>>(wtsb, 256, supT, 64, yb, 0);
  graph_gemm<64, 7><<<dim3(4, 6, NB), 256, 0, stream>>>(wtsbT, 64, supT, 0, yb, 64);

  // 13) out = y + LN(y)
  ln_final<<<MROWS, 192, 0, stream>>>(yb, g3, b3, out);
}

// Round 4
// 477.381 us; speedup vs baseline: 1.3002x; 1.3002x over previous
//
#include <hip/hip_runtime.h>
#include <stdint.h>

#define NB 32      // batch
#define NSEQ 320   // tokens
#define CDIM 768
#define NH 12
#define HD 64
#define MLPH 3072
#define MROWS (NB*NSEQ)   // 10240

typedef __attribute__((ext_vector_type(8))) short v8s;
typedef __attribute__((ext_vector_type(4))) float v4f;

__device__ __forceinline__ unsigned short f2b(float f){
  unsigned int u = __float_as_uint(f);
  u += 0x7fffu + ((u >> 16) & 1u);
  return (unsigned short)(u >> 16);
}
__device__ __forceinline__ float b2f(unsigned short h){
  return __uint_as_float(((unsigned int)h) << 16);
}
__device__ __forceinline__ void glds16(const unsigned short* g, unsigned short* l){
  __builtin_amdgcn_global_load_lds(
      (const __attribute__((address_space(1))) void*)g,
      (__attribute__((address_space(3))) void*)l, 16, 0, 0);
}

// ---------------- all weight casts in ONE dispatch ----------------------------
// W (K,N) f32 -> Wt (N,K) bf16, 32x32 tiles; 5 weights packed by block ranges.
__global__ __launch_bounds__(256)
void castAll(const float* __restrict__ Wqkv, const float* __restrict__ Wproj,
             const float* __restrict__ W1,   const float* __restrict__ W2,
             const float* __restrict__ Wg,
             unsigned short* __restrict__ wqkvT, unsigned short* __restrict__ wprojT,
             unsigned short* __restrict__ w1T,   unsigned short* __restrict__ w2T,
             unsigned short* __restrict__ wgT){
  // tiles: qkv 24x72=1728 | proj 24x24=576 | W1 24x96=2304 | W2 96x24=2304 | Wg 576
  int bid = blockIdx.x;
  const float* W; unsigned short* Wt; int K, N, KT;
  if (bid < 1728){ W = Wqkv; Wt = wqkvT; K = 768; N = 2304; KT = 24; }
  else if (bid < 1728+576){ bid -= 1728; W = Wproj; Wt = wprojT; K = 768; N = 768; KT = 24; }
  else if (bid < 1728+576+2304){ bid -= 1728+576; W = W1; Wt = w1T; K = 768; N = 3072; KT = 24; }
  else if (bid < 1728+576+2304+2304){ bid -= 1728+576+2304; W = W2; Wt = w2T; K = 3072; N = 768; KT = 96; }
  else { bid -= 1728+576+2304+2304; W = Wg; Wt = wgT; K = 768; N = 768; KT = 24; }
  const int k0 = (bid % KT) * 32, n0 = (bid / KT) * 32;
  __shared__ float tile[32][33];
  const int tx = threadIdx.x & 31, ty = threadIdx.x >> 5;   // ty 0..7
  #pragma unroll
  for (int i = 0; i < 32; i += 8)
    tile[ty + i][tx] = W[(size_t)(k0 + ty + i) * N + n0 + tx];
  __syncthreads();
  #pragma unroll
  for (int i = 0; i < 32; i += 8)
    Wt[(size_t)(n0 + ty + i) * K + k0 + tx] = f2b(tile[tx][ty + i]);
}

// ---------------- row LayerNorm (f32 in) -> bf16 out --------------------------
__global__ __launch_bounds__(192)
void ln_to_bf16(const float* __restrict__ x, const float* __restrict__ g,
                const float* __restrict__ be, unsigned short* __restrict__ out){
  const int row = blockIdx.x;
  const int t = threadIdx.x, w = t >> 6, l = t & 63;
  const float4 v = *(const float4*)(x + (size_t)row * CDIM + t * 4);
  float s  = v.x + v.y + v.z + v.w;
  float s2 = v.x*v.x + v.y*v.y + v.z*v.z + v.w*v.w;
  __shared__ float r1[3], r2[3];
  #pragma unroll
  for (int d = 1; d < 64; d <<= 1){ s += __shfl_xor(s, d, 64); s2 += __shfl_xor(s2, d, 64); }
  if (l == 0){ r1[w] = s; r2[w] = s2; }
  __syncthreads();
  const float S = r1[0] + r1[1] + r1[2];
  const float S2 = r2[0] + r2[1] + r2[2];
  const float mean = S * (1.0f / CDIM);
  const float var  = S2 * (1.0f / CDIM) - mean * mean;
  const float rs = rsqrtf(var + 1e-5f);
  const float4 gg = *(const float4*)(g + t * 4);
  const float4 bb = *(const float4*)(be + t * 4);
  ushort4 o;
  o.x = f2b((v.x - mean) * rs * gg.x + bb.x);
  o.y = f2b((v.y - mean) * rs * gg.y + bb.y);
  o.z = f2b((v.z - mean) * rs * gg.z + bb.z);
  o.w = f2b((v.w - mean) * rs * gg.w + bb.w);
  *(ushort4*)(out + (size_t)row * CDIM + t * 4) = o;
}

// ---------- 2-phase 128x128 bf16 MFMA GEMM, BK=64, swizzled LDS ---------------
// C = A(M,K) @ Bt(N,K)^T.  4 waves (2x2), acc 4x4 frags/wave.
// XOR-involution swizzle: pre-swizzled global_load_lds source + swizzled
// ds_read_b128 address (byte ^ (row&7)<<4) -> conflict-free at 128B row stride.
template<bool BIAS, bool RES, bool GELU, bool WB, bool WF>
__global__ __launch_bounds__(256, 2)
void gemm_bt64(const unsigned short* __restrict__ A, const unsigned short* __restrict__ Bt,
               int N, int K,
               const float* __restrict__ bias, const float* __restrict__ res,
               unsigned short* __restrict__ outb, float* __restrict__ outf){
  __shared__ __align__(16) unsigned short As[128 * 64];
  __shared__ __align__(16) unsigned short Bs[128 * 64];
  const int t = threadIdx.x;
  const int w = t >> 6, l = t & 63;
  const int bm = blockIdx.x, bn = blockIdx.y;
  const int wr = w >> 1, wc = w & 1;
  v4f acc[4][4] = {};

  const int srow = w * 32 + (l >> 3);              // wave stages rows [32w,32w+32)
  const int scol = ((l & 7) ^ (l >> 3)) * 8;       // pre-swizzled source (elems)
  const unsigned short* Ag = A + (size_t)(bm * 128 + srow) * K + scol;
  const unsigned short* Bg = Bt + (size_t)(bn * 128 + srow) * K + scol;
  unsigned short* Al = As + (w * 32) * 64;
  unsigned short* Bl = Bs + (w * 32) * 64;

  const int nkt = K >> 6;
  for (int kt = 0; kt < nkt; ++kt){
    const int k0 = kt << 6;
    if (kt) __syncthreads();
    #pragma unroll
    for (int i = 0; i < 4; ++i){
      glds16(Ag + (size_t)(i * 8) * K + k0, Al + i * 8 * 64);
      glds16(Bg + (size_t)(i * 8) * K + k0, Bl + i * 8 * 64);
    }
    __syncthreads();
    #pragma unroll
    for (int ks = 0; ks < 2; ++ks){
      const int kb = ks * 64 + ((l >> 4) << 4);    // byte col offset
      v8s af[4], bfr[4];
      #pragma unroll
      for (int mi = 0; mi < 4; ++mi){
        const int r = wr * 64 + mi * 16 + (l & 15);
        af[mi] = *(const v8s*)((const char*)As + r * 128 + (kb ^ ((r & 7) << 4)));
      }
      #pragma unroll
      for (int ni = 0; ni < 4; ++ni){
        const int r = wc * 64 + ni * 16 + (l & 15);
        bfr[ni] = *(const v8s*)((const char*)Bs + r * 128 + (kb ^ ((r & 7) << 4)));
      }
      #pragma unroll
      for (int mi = 0; mi < 4; ++mi)
        #pragma unroll
        for (int ni = 0; ni < 4; ++ni)
          acc[mi][ni] = __builtin_amdgcn_mfma_f32_16x16x32_bf16(af[mi], bfr[ni], acc[mi][ni], 0, 0, 0);
    }
  }

  const int r0 = bm * 128 + wr * 64 + ((l >> 4) << 2);
  const int c0 = bn * 128 + wc * 64 + (l & 15);
  #pragma unroll
  for (int mi = 0; mi < 4; ++mi){
    #pragma unroll
    for (int rr = 0; rr < 4; ++rr){
      const int row = r0 + mi * 16 + rr;
      #pragma unroll
      for (int ni = 0; ni < 4; ++ni){
        const int col = c0 + ni * 16;
        float c = acc[mi][ni][rr];
        if (BIAS) c += bias[col];
        if (RES)  c += res[(size_t)row * N + col];
        if (GELU) c = 0.5f * c * (1.0f + erff(c * 0.70710678118f));
        if (WB) outb[(size_t)row * N + col] = f2b(c);
        if (WF) outf[(size_t)row * N + col] = c;
      }
    }
  }
}

// ---------------- attention: per (b,h,qtile of 64 rows) -----------------------
// qkv layout: [(b*320+n)*2304 + s*768 + h*64 + d], bf16
__global__ __launch_bounds__(256, 2)
void attn_kernel(const unsigned short* __restrict__ qkv,
                 unsigned short* __restrict__ ctx,
                 float* __restrict__ wparts){
  __shared__ __align__(16) unsigned short Qs[64 * 72];
  __shared__ __align__(16) unsigned short KV[64 * 72];   // K tile, then V^T tile
  __shared__ __align__(16) unsigned short Ps[64 * 328];
  const int t = threadIdx.x;
  const int w = t >> 6, l = t & 63;
  const int bid = blockIdx.x;
  const int qt = bid % 5;
  const int h  = (bid / 5) % NH;
  const int b  = bid / (5 * NH);
  const size_t base = (size_t)b * NSEQ * 2304 + h * 64;

  { // stage Q (64 x 64)
    const int r = t >> 3, seg = t & 7;
    #pragma unroll
    for (int i = 0; i < 2; ++i){
      const int r2 = r + 32 * i;
      const unsigned short* src = qkv + base + (size_t)(qt * 64 + r2) * 2304 + seg * 8;
      *(uint4*)&Qs[r2 * 72 + seg * 8] = *(const uint4*)src;
    }
  }
  __syncthreads();
  const int qr = 16 * w + (l & 15);
  const v8s aq0 = *(const v8s*)&Qs[qr * 72 + ((l >> 4) << 3)];
  const v8s aq1 = *(const v8s*)&Qs[qr * 72 + 32 + ((l >> 4) << 3)];

  v4f sacc[20] = {};
  for (int kt = 0; kt < 5; ++kt){
    __syncthreads();
    { // stage K tile
      const int r = t >> 3, seg = t & 7;
      #pragma unroll
      for (int i = 0; i < 2; ++i){
        const int r2 = r + 32 * i;
        const unsigned short* src = qkv + base + 768 + (size_t)(kt * 64 + r2) * 2304 + seg * 8;
        *(uint4*)&KV[r2 * 72 + seg * 8] = *(const uint4*)src;
      }
    }
    __syncthreads();
    #pragma unroll
    for (int f = 0; f < 4; ++f){
      const int kr = 16 * f + (l & 15);
      const v8s b0 = *(const v8s*)&KV[kr * 72 + ((l >> 4) << 3)];
      const v8s b1 = *(const v8s*)&KV[kr * 72 + 32 + ((l >> 4) << 3)];
      sacc[kt * 4 + f] = __builtin_amdgcn_mfma_f32_16x16x32_bf16(aq0, b0, sacc[kt * 4 + f], 0, 0, 0);
      sacc[kt * 4 + f] = __builtin_amdgcn_mfma_f32_16x16x32_bf16(aq1, b1, sacc[kt * 4 + f], 0, 0, 0);
    }
  }

  // wave-parallel softmax; rows live in 16-lane groups (xor 1,2,4,8 stays in-group)
  const float scale = 0.125f;
  #pragma unroll
  for (int r = 0; r < 4; ++r){
    float m = -1e30f;
    #pragma unroll
    for (int f = 0; f < 20; ++f) m = fmaxf(m, sacc[f][r]);
    #pragma unroll
    for (int d = 1; d < 16; d <<= 1) m = fmaxf(m, __shfl_xor(m, d, 64));
    const float Ms = m * scale;
    float sum = 0.f;
    #pragma unroll
    for (int f = 0; f < 20; ++f){ float p = expf(sacc[f][r] * scale - Ms); sacc[f][r] = p; sum += p; }
    #pragma unroll
    for (int d = 1; d < 16; d <<= 1) sum += __shfl_xor(sum, d, 64);
    const float inv = 1.0f / sum;
    const int rowq = 16 * w + ((l >> 4) << 2) + r;
    #pragma unroll
    for (int f = 0; f < 20; ++f)
      Ps[rowq * 328 + f * 16 + (l & 15)] = f2b(sacc[f][r] * inv);
    if (qt == 0){
      #pragma unroll
      for (int f = 4; f < 20; ++f)
        wparts[(((size_t)b * NH + h) * 64 + rowq) * 256 + (f - 4) * 16 + (l & 15)] = sacc[f][r] * inv;
    }
  }

  // P @ V
  v4f cacc[4] = {};
  for (int kt = 0; kt < 5; ++kt){
    __syncthreads();
    { // stage V^T tile: KV[d*72 + m] = V[m][d]
      const int m = t & 31, d0 = (t >> 5) * 8;
      #pragma unroll
      for (int i = 0; i < 2; ++i){
        const int m2 = m + 32 * i;
        const unsigned short* src = qkv + base + 1536 + (size_t)(kt * 64 + m2) * 2304 + d0;
        uint4 dv = *(const uint4*)src;
        const unsigned short* e = (const unsigned short*)&dv;
        #pragma unroll
        for (int jj = 0; jj < 8; ++jj) KV[(d0 + jj) * 72 + m2] = e[jj];
      }
    }
    __syncthreads();
    const int pr = 16 * w + (l & 15);
    const v8s pa0 = *(const v8s*)&Ps[pr * 328 + kt * 64 + ((l >> 4) << 3)];
    const v8s pa1 = *(const v8s*)&Ps[pr * 328 + kt * 64 + 32 + ((l >> 4) << 3)];
    #pragma unroll
    for (int f = 0; f < 4; ++f){
      const int vc = 16 * f + (l & 15);
      const v8s bv0 = *(const v8s*)&KV[vc * 72 + ((l >> 4) << 3)];
      const v8s bv1 = *(const v8s*)&KV[vc * 72 + 32 + ((l >> 4) << 3)];
      cacc[f] = __builtin_amdgcn_mfma_f32_16x16x32_bf16(pa0, bv0, cacc[f], 0, 0, 0);
      cacc[f] = __builtin_amdgcn_mfma_f32_16x16x32_bf16(pa1, bv1, cacc[f], 0, 0, 0);
    }
  }
  #pragma unroll
  for (int f = 0; f < 4; ++f)
    #pragma unroll
    for (int rr = 0; rr < 4; ++rr){
      const int rowq = 16 * w + ((l >> 4) << 2) + rr;
      const int col = 16 * f + (l & 15);
      ctx[(size_t)(b * NSEQ + qt * 64 + rowq) * CDIM + h * 64 + col] = f2b(cacc[f][rr]);
    }
}

// ---------------- w_ts: sum over heads /H then softmax over 256; bf16 x2 ------
__global__ __launch_bounds__(256)
void wts_softmax(const float* __restrict__ wparts,
                 unsigned short* __restrict__ wtsb,
                 unsigned short* __restrict__ wtsbT){
  const int row = blockIdx.x;            // b*64 + n
  const int b = row >> 6, n = row & 63;
  const int j = threadIdx.x;
  const int w = j >> 6, l = j & 63;
  float s = 0.f;
  #pragma unroll
  for (int hh = 0; hh < NH; ++hh)
    s += wparts[(((size_t)b * NH + hh) * 64 + n) * 256 + j];
  s *= (1.0f / NH);
  __shared__ float red[8];
  float m = s;
  #pragma unroll
  for (int d = 1; d < 64; d <<= 1) m = fmaxf(m, __shfl_xor(m, d, 64));
  if (l == 0) red[w] = m;
  __syncthreads();
  m = fmaxf(fmaxf(red[0], red[1]), fmaxf(red[2], red[3]));
  const float e = expf(s - m);
  float sm = e;
  #pragma unroll
  for (int d = 1; d < 64; d <<= 1) sm += __shfl_xor(sm, d, 64);
  if (l == 0) red[4 + w] = sm;
  __syncthreads();
  const float tot = red[4] + red[5] + red[6] + red[7];
  const unsigned short p = f2b(e / tot);
  wtsb [((size_t)b * 64 + n) * 256 + j] = p;
  wtsbT[((size_t)b * 256 + j) * 64 + n] = p;
}

// ---------------- support transpose: (b,320,768) -> (b,768,320) bf16 ----------
__global__ __launch_bounds__(256)
void transT(const unsigned short* __restrict__ in, unsigned short* __restrict__ out){
  __shared__ unsigned short tile[64][65];   // [c][n]
  const int c0 = blockIdx.x * 64, n0 = blockIdx.y * 64, b = blockIdx.z;
  const int tx = threadIdx.x & 31, ty = threadIdx.x >> 5;  // ty 0..7
  const unsigned short* ib = in + (size_t)b * NSEQ * CDIM;
  unsigned short* ob = out + (size_t)b * CDIM * NSEQ;
  #pragma unroll
  for (int i = 0; i < 64; i += 8){
    const unsigned int v = *(const unsigned int*)&ib[(size_t)(n0 + ty + i) * CDIM + c0 + tx * 2];
    tile[tx * 2][ty + i]     = (unsigned short)(v & 0xffff);
    tile[tx * 2 + 1][ty + i] = (unsigned short)(v >> 16);
  }
  __syncthreads();
  #pragma unroll
  for (int i = 0; i < 64; i += 8){
    const int c = ty + i;
    const unsigned int v = (unsigned int)tile[c][tx * 2] | ((unsigned int)tile[c][tx * 2 + 1] << 16);
    *(unsigned int*)&ob[(size_t)(c0 + c) * NSEQ + n0 + tx * 2] = v;
  }
}

// ---------------- graph matmul via MFMA ---------------------------------------
template<int KC, int SH2>   // KC = K-chunk, SH2 = log2(KC*2)
__global__ __launch_bounds__(256, 2)
void graph_gemm(const unsigned short* __restrict__ A, int KTOT,
                const unsigned short* __restrict__ supT, int koff,
                float* __restrict__ y, int rowoff){
  __shared__ __align__(16) unsigned short As[64 * KC];
  __shared__ __align__(16) unsigned short Bs[128 * KC];
  const int t = threadIdx.x, w = t >> 6, l = t & 63;
  const int mt = blockIdx.x, ct = blockIdx.y, b = blockIdx.z;
  const char* Ab = (const char*)(A + (size_t)b * 16384 + (size_t)mt * 64 * KTOT);
  const char* Bb = (const char*)(supT + (size_t)b * CDIM * NSEQ);
  v4f acc[4][2] = {};

  const int nch = KTOT / KC;
  for (int ch = 0; ch < nch; ++ch){
    if (ch) __syncthreads();
    const int kbase = (koff + ch * KC) * 2;   // byte offset into supT row
    #pragma unroll
    for (int i = 0; i < KC / 32; ++i){        // stage A chunk (swizzled)
      const int gi = w * (KC / 32) + i;
      const int X = gi * 1024 + l * 16;
      const int c = X >> SH2;
      const int k2 = (X & (KC * 2 - 1)) ^ ((c & 7) << 4);
      glds16((const unsigned short*)(Ab + (size_t)c * (KTOT * 2) + ch * KC * 2 + k2),
             As + (gi * 512));
    }
    #pragma unroll
    for (int i = 0; i < KC / 16; ++i){        // stage B chunk (swizzled)
      const int gi = w * (KC / 16) + i;
      const int X = gi * 1024 + l * 16;
      const int c = X >> SH2;
      const int k2 = (X & (KC * 2 - 1)) ^ ((c & 7) << 4);
      glds16((const unsigned short*)(Bb + (size_t)(ct * 128 + c) * (NSEQ * 2) + kbase + k2),
             Bs + (gi * 512));
    }
    __syncthreads();
    #pragma unroll
    for (int ks = 0; ks < KC / 32; ++ks){
      const int kbyte = ks * 64 + ((l >> 4) << 4);
      v8s af[4], bf2[2];
      #pragma unroll
      for (int mi = 0; mi < 4; ++mi){
        const int r = mi * 16 + (l & 15);
        af[mi] = *(const v8s*)((const char*)As + (r << SH2) + (kbyte ^ ((r & 7) << 4)));
      }
      #pragma unroll
      for (int ni = 0; ni < 2; ++ni){
        const int rb = w * 32 + ni * 16 + (l & 15);
        bf2[ni] = *(const v8s*)((const char*)Bs + (rb << SH2) + (kbyte ^ ((rb & 7) << 4)));
      }
      #pragma unroll
      for (int mi = 0; mi < 4; ++mi)
        #pragma unroll
        for (int ni = 0; ni < 2; ++ni)
          acc[mi][ni] = __builtin_amdgcn_mfma_f32_16x16x32_bf16(af[mi], bf2[ni], acc[mi][ni], 0, 0, 0);
    }
  }

  const int r0 = rowoff + mt * 64 + ((l >> 4) << 2);
  const int c0 = ct * 128 + w * 32 + (l & 15);
  #pragma unroll
  for (int mi = 0; mi < 4; ++mi)
    #pragma unroll
    for (int ni = 0; ni < 2; ++ni)
      #pragma unroll
      for (int rr = 0; rr < 4; ++rr)
        y[((size_t)b * NSEQ + r0 + mi * 16 + rr) * CDIM + c0 + ni * 16] = acc[mi][ni][rr];
}

// ---------------- final: out = y + LN(y) --------------------------------------
__global__ __launch_bounds__(192)
void ln_final(const float* __restrict__ y, const float* __restrict__ g3,
              const float* __restrict__ b3, float* __restrict__ out){
  const int row = blockIdx.x;
  const int t = threadIdx.x, w = t >> 6, l = t & 63;
  const float4 v = *(const float4*)(y + (size_t)row * CDIM + t * 4);
  float s  = v.x + v.y + v.z + v.w;
  float s2 = v.x*v.x + v.y*v.y + v.z*v.z + v.w*v.w;
  __shared__ float r1[3], r2[3];
  #pragma unroll
  for (int d = 1; d < 64; d <<= 1){ s += __shfl_xor(s, d, 64); s2 += __shfl_xor(s2, d, 64); }
  if (l == 0){ r1[w] = s; r2[w] = s2; }
  __syncthreads();
  const float S = r1[0] + r1[1] + r1[2];
  const float S2 = r2[0] + r2[1] + r2[2];
  const float mean = S * (1.0f / CDIM);
  const float var  = S2 * (1.0f / CDIM) - mean * mean;
  const float rs = rsqrtf(var + 1e-5f);
  const float4 gg = *(const float4*)(g3 + t * 4);
  const float4 bb = *(const float4*)(b3 + t * 4);
  float4 o;
  o.x = v.x + (v.x - mean) * rs * gg.x + bb.x;
  o.y = v.y + (v.y - mean) * rs * gg.y + bb.y;
  o.z = v.z + (v.z - mean) * rs * gg.z + bb.z;
  o.w = v.w + (v.w - mean) * rs * gg.w + bb.w;
  *(float4*)(out + (size_t)row * CDIM + t * 4) = o;
}

extern "C" void kernel_launch(void* const* d_in, const int* in_sizes, int n_in,
                              void* d_out, int out_size, void* d_ws, size_t ws_size,
                              hipStream_t stream){
  (void)in_sizes; (void)n_in; (void)out_size; (void)ws_size;
  const float* x    = (const float*)d_in[0];
  const float* g1   = (const float*)d_in[3];
  const float* b1   = (const float*)d_in[4];
  const float* Wqkv = (const float*)d_in[5];
  const float* Wproj= (const float*)d_in[6];
  const float* bproj= (const float*)d_in[7];
  const float* g2   = (const float*)d_in[8];
  const float* b2   = (const float*)d_in[9];
  const float* W1   = (const float*)d_in[10];
  const float* bm1  = (const float*)d_in[11];
  const float* W2   = (const float*)d_in[12];
  const float* bm2  = (const float*)d_in[13];
  const float* Wg   = (const float*)d_in[14];
  const float* bg   = (const float*)d_in[15];
  const float* g3   = (const float*)d_in[16];
  const float* b3   = (const float*)d_in[17];
  float* out = (float*)d_out;
  char* ws = (char*)d_ws;

  // workspace layout (bytes); aliases are time-disjoint
  unsigned short* wqkvT = (unsigned short*)(ws + 0);          // 3,538,944
  unsigned short* wprojT= (unsigned short*)(ws + 3538944);    // 1,179,648
  unsigned short* w1T   = (unsigned short*)(ws + 4718592);    // 4,718,592
  unsigned short* w2T   = (unsigned short*)(ws + 9437184);    // 4,718,592
  unsigned short* wgT   = (unsigned short*)(ws + 14155776);   // 1,179,648
  unsigned short* xn1   = (unsigned short*)(ws + 15335424);   // 15,728,640
  unsigned short* qkvb  = (unsigned short*)(ws + 31064064);   // 47,185,920
  unsigned short* hb    = (unsigned short*)(ws + 15335424);   // aliases xn1+qkv
  unsigned short* supT  = (unsigned short*)(ws + 15335424);   // aliases hb (dead after MLP2)
  unsigned short* ctxb  = (unsigned short*)(ws + 78249984);   // 15,728,640
  unsigned short* x2b   = (unsigned short*)(ws + 78249984);   // aliases ctx
  unsigned short* xn2   = (unsigned short*)(ws + 93978624);   // 15,728,640
  unsigned short* supb  = (unsigned short*)(ws + 93978624);   // aliases xn2
  float*          x1    = (float*)(ws + 109707264);           // 31,457,280
  float*          wparts= (float*)(ws + 109707264);           // aliases x1
  float*          yb    = (float*)(ws + 109707264);           // aliases x1 (dead after MLP2)
  unsigned short* wtsb  = (unsigned short*)(ws + 141164544);  // 1,048,576
  unsigned short* wtsbT = (unsigned short*)(ws + 142213120);  // 1,048,576

  // 1) all weights -> bf16 transposed, one dispatch
  castAll<<<7488, 256, 0, stream>>>(Wqkv, Wproj, W1, W2, Wg,
                                    wqkvT, wprojT, w1T, w2T, wgT);

  // 2) LN1 -> bf16
  ln_to_bf16<<<MROWS, 192, 0, stream>>>(x, g1, b1, xn1);

  // 3) QKV GEMM (no bias): M=10240, N=2304, K=768
  gemm_bt64<false,false,false,true,false><<<dim3(80, 18), 256, 0, stream>>>(
      xn1, wqkvT, 2304, CDIM, nullptr, nullptr, qkvb, nullptr);

  // 4) attention (also emits per-head prob slices for w_ts)
  attn_kernel<<<NB * NH * 5, 256, 0, stream>>>(qkvb, ctxb, wparts);

  // 5) w_ts = softmax(sum_h attn[:,:64,64:]/H), bf16 in both orientations
  //    (must run before proj: wparts aliases x1)
  wts_softmax<<<NB * 64, 256, 0, stream>>>(wparts, wtsb, wtsbT);

  // 6) proj + bias + residual(x) -> x1 (f32)
  gemm_bt64<true,true,false,false,true><<<dim3(80, 6), 256, 0, stream>>>(
      ctxb, wprojT, CDIM, CDIM, bproj, x, nullptr, x1);

  // 7) LN2 -> bf16
  ln_to_bf16<<<MROWS, 192, 0, stream>>>(x1, g2, b2, xn2);

  // 8) MLP1 + bias + exact GELU -> h (bf16): N=3072, K=768
  gemm_bt64<true,false,true,true,false><<<dim3(80, 24), 256, 0, stream>>>(
      xn2, w1T, MLPH, CDIM, bm1, nullptr, hb, nullptr);

  // 9) MLP2 + bias + residual(x1) -> x2 (bf16): N=768, K=3072
  gemm_bt64<true,true,false,true,false><<<dim3(80, 6), 256, 0, stream>>>(
      hb, w2T, CDIM, MLPH, bm2, x1, x2b, nullptr);

  // 10) support = x2 @ Wg + bg (bf16)
  gemm_bt64<true,false,false,true,false><<<dim3(80, 6), 256, 0, stream>>>(
      x2b, wgT, CDIM, CDIM, bg, nullptr, supb, nullptr);

  // 11) supT = transpose(support) per batch
  transT<<<dim3(CDIM/64, NSEQ/64, NB), 256, 0, stream>>>(supb, supT);

  // 12) y = adj @ support via two batched MFMA GEMMs
  graph_gemm<128, 8><<<dim3(1, 6, NB), 256, 0, stream>>>(wtsb, 256, supT, 64, yb, 0);
  graph_gemm<64, 7><<<dim3(4, 6, NB), 256, 0, stream>>>(wtsbT, 64, supT, 0, yb, 64);

  // 13) out = y + LN(y)
  ln_final<<<MROWS, 192, 0, stream>>>(yb, g3, b3, out);
}

// Round 6
// 477.268 us; speedup vs baseline: 1.3005x; 1.0002x over previous
//
#include <hip/hip_runtime.h>
#include <stdint.h>

#define NB 32      // batch
#define NSEQ 320   // tokens
#define CDIM 768
#define NH 12
#define HD 64
#define MLPH 3072
#define MROWS (NB*NSEQ)   // 10240

typedef __attribute__((ext_vector_type(8))) short v8s;
typedef __attribute__((ext_vector_type(4))) float v4f;

__device__ __forceinline__ unsigned short f2b(float f){
  unsigned int u = __float_as_uint(f);
  u += 0x7fffu + ((u >> 16) & 1u);
  return (unsigned short)(u >> 16);
}
__device__ __forceinline__ float b2f(unsigned short h){
  return __uint_as_float(((unsigned int)h) << 16);
}
__device__ __forceinline__ void glds16(const unsigned short* g, unsigned short* l){
  __builtin_amdgcn_global_load_lds(
      (const __attribute__((address_space(1))) void*)g,
      (__attribute__((address_space(3))) void*)l, 16, 0, 0);
}

// ---------------- all weight casts in ONE dispatch ----------------------------
__global__ __launch_bounds__(256)
void castAll(const float* __restrict__ Wqkv, const float* __restrict__ Wproj,
             const float* __restrict__ W1,   const float* __restrict__ W2,
             const float* __restrict__ Wg,
             unsigned short* __restrict__ wqkvT, unsigned short* __restrict__ wprojT,
             unsigned short* __restrict__ w1T,   unsigned short* __restrict__ w2T,
             unsigned short* __restrict__ wgT){
  int bid = blockIdx.x;
  const float* W; unsigned short* Wt; int K, N, KT;
  if (bid < 1728){ W = Wqkv; Wt = wqkvT; K = 768; N = 2304; KT = 24; }
  else if (bid < 1728+576){ bid -= 1728; W = Wproj; Wt = wprojT; K = 768; N = 768; KT = 24; }
  else if (bid < 1728+576+2304){ bid -= 1728+576; W = W1; Wt = w1T; K = 768; N = 3072; KT = 24; }
  else if (bid < 1728+576+2304+2304){ bid -= 1728+576+2304; W = W2; Wt = w2T; K = 3072; N = 768; KT = 96; }
  else { bid -= 1728+576+2304+2304; W = Wg; Wt = wgT; K = 768; N = 768; KT = 24; }
  const int k0 = (bid % KT) * 32, n0 = (bid / KT) * 32;
  __shared__ float tile[32][33];
  const int tx = threadIdx.x & 31, ty = threadIdx.x >> 5;
  #pragma unroll
  for (int i = 0; i < 32; i += 8)
    tile[ty + i][tx] = W[(size_t)(k0 + ty + i) * N + n0 + tx];
  __syncthreads();
  #pragma unroll
  for (int i = 0; i < 32; i += 8)
    Wt[(size_t)(n0 + ty + i) * K + k0 + tx] = f2b(tile[tx][ty + i]);
}

// ---------------- row LayerNorm (f32 in) -> bf16 out --------------------------
__global__ __launch_bounds__(192)
void ln_to_bf16(const float* __restrict__ x, const float* __restrict__ g,
                const float* __restrict__ be, unsigned short* __restrict__ out){
  const int row = blockIdx.x;
  const int t = threadIdx.x, w = t >> 6, l = t & 63;
  const float4 v = *(const float4*)(x + (size_t)row * CDIM + t * 4);
  float s  = v.x + v.y + v.z + v.w;
  float s2 = v.x*v.x + v.y*v.y + v.z*v.z + v.w*v.w;
  __shared__ float r1[3], r2[3];
  #pragma unroll
  for (int d = 1; d < 64; d <<= 1){ s += __shfl_xor(s, d, 64); s2 += __shfl_xor(s2, d, 64); }
  if (l == 0){ r1[w] = s; r2[w] = s2; }
  __syncthreads();
  const float S = r1[0] + r1[1] + r1[2];
  const float S2 = r2[0] + r2[1] + r2[2];
  const float mean = S * (1.0f / CDIM);
  const float var  = S2 * (1.0f / CDIM) - mean * mean;
  const float rs = rsqrtf(var + 1e-5f);
  const float4 gg = *(const float4*)(g + t * 4);
  const float4 bb = *(const float4*)(be + t * 4);
  ushort4 o;
  o.x = f2b((v.x - mean) * rs * gg.x + bb.x);
  o.y = f2b((v.y - mean) * rs * gg.y + bb.y);
  o.z = f2b((v.z - mean) * rs * gg.z + bb.z);
  o.w = f2b((v.w - mean) * rs * gg.w + bb.w);
  *(ushort4*)(out + (size_t)row * CDIM + t * 4) = o;
}

// ======== counted-vmcnt 128x128 bf16 MFMA GEMM, BK=32, triple-buffer =========
// C = A(M,K) @ Bt(N,K)^T. 4 waves (2x2), acc 4x4 frags/wave.
// Pipeline: iter t { stage(t+2) ; ds_read(t) ; 16 MFMA ; vmcnt(4) ; barrier }.
// vmcnt(4) retires tile t+1's 4 loads (t+2's stay in flight) BEFORE the
// barrier that publishes the buffer -> per-wave vmcnt + barrier = publish.
// Requires (K/32) % 3 == 0 (true for K in {768, 3072}).
template<bool BIAS, bool RES, bool GELU, bool WB, bool WF>
__global__ __launch_bounds__(256, 3)
void gemm_cv(const unsigned short* __restrict__ A, const unsigned short* __restrict__ Bt,
             int N, int K,
             const float* __restrict__ bias, const float* __restrict__ res,
             unsigned short* __restrict__ outb, float* __restrict__ outf){
  __shared__ __align__(16) unsigned short lds[3 * 8192];   // buf = A(128x32) + B(128x32)
  const int tid = threadIdx.x;
  const int w = tid >> 6, l = tid & 63;
  const int bm = blockIdx.x, bn = blockIdx.y;
  const int wr = w >> 1, wc = w & 1;
  const int nkt = K >> 5;
  v4f acc[4][4] = {};

  const int srow = w * 32 + (l >> 2);        // stage row (+ i*16)
  const int scol = (l & 3) * 8;
  const unsigned short* Ag = A + (size_t)(bm * 128 + srow) * K + scol;
  const unsigned short* Bg = Bt + (size_t)(bn * 128 + srow) * K + scol;
  const int ldst = (w * 32) * 32;            // wave-uniform LDS dest (+ i*512)

  auto stage = [&](int bufi, int kt){
    unsigned short* Ab = lds + bufi * 8192;
    #pragma unroll
    for (int i = 0; i < 2; ++i){
      glds16(Ag + (size_t)(i * 16) * K + kt * 32, Ab + ldst + i * 512);
      glds16(Bg + (size_t)(i * 16) * K + kt * 32, Ab + 4096 + ldst + i * 512);
    }
  };

  auto body = [&](int kt, int cbuf){
    if (kt + 2 < nkt) stage((cbuf + 2) % 3, kt + 2);
    const unsigned short* Ab = lds + cbuf * 8192;
    const unsigned short* Bb = Ab + 4096;
    const int kk = (l >> 4) << 3;
    v8s af[4], bfr[4];
    #pragma unroll
    for (int mi = 0; mi < 4; ++mi)
      af[mi] = *(const v8s*)&Ab[(wr * 64 + mi * 16 + (l & 15)) * 32 + kk];
    #pragma unroll
    for (int ni = 0; ni < 4; ++ni)
      bfr[ni] = *(const v8s*)&Bb[(wc * 64 + ni * 16 + (l & 15)) * 32 + kk];
    __builtin_amdgcn_s_setprio(1);
    #pragma unroll
    for (int mi = 0; mi < 4; ++mi)
      #pragma unroll
      for (int ni = 0; ni < 4; ++ni)
        acc[mi][ni] = __builtin_amdgcn_mfma_f32_16x16x32_bf16(af[mi], bfr[ni], acc[mi][ni], 0, 0, 0);
    __builtin_amdgcn_s_setprio(0);
    if (kt + 2 < nkt)      asm volatile("s_waitcnt vmcnt(4)" ::: "memory");
    else if (kt + 1 < nkt) asm volatile("s_waitcnt vmcnt(0)" ::: "memory");
    if (kt + 1 < nkt) __builtin_amdgcn_s_barrier();
  };

  // prologue: tiles 0,1 staged; publish tile 0
  stage(0, 0); stage(1, 1);
  asm volatile("s_waitcnt vmcnt(4)" ::: "memory");
  __builtin_amdgcn_s_barrier();

  #pragma unroll 1
  for (int base = 0; base < nkt; base += 3){
    body(base + 0, 0);
    body(base + 1, 1);
    body(base + 2, 2);
  }

  const int r0 = bm * 128 + wr * 64 + ((l >> 4) << 2);
  const int c0 = bn * 128 + wc * 64 + (l & 15);
  #pragma unroll
  for (int mi = 0; mi < 4; ++mi){
    #pragma unroll
    for (int rr = 0; rr < 4; ++rr){
      const int row = r0 + mi * 16 + rr;
      #pragma unroll
      for (int ni = 0; ni < 4; ++ni){
        const int col = c0 + ni * 16;
        float c = acc[mi][ni][rr];
        if (BIAS) c += bias[col];
        if (RES)  c += res[(size_t)row * N + col];
        if (GELU) c = 0.5f * c * (1.0f + erff(c * 0.70710678118f));
        if (WB) outb[(size_t)row * N + col] = f2b(c);
        if (WF) outf[(size_t)row * N + col] = c;
      }
    }
  }
}

// ---------------- attention: per (b,h,qtile of 64 rows) -----------------------
// qkv layout: [(b*320+n)*2304 + s*768 + h*64 + d], bf16
__global__ __launch_bounds__(256, 2)
void attn_kernel(const unsigned short* __restrict__ qkv,
                 unsigned short* __restrict__ ctx,
                 float* __restrict__ wparts){
  __shared__ __align__(16) unsigned short Qs[64 * 72];
  __shared__ __align__(16) unsigned short KV[64 * 72];   // K tile, then V^T tile
  __shared__ __align__(16) unsigned short Ps[64 * 328];
  const int t = threadIdx.x;
  const int w = t >> 6, l = t & 63;
  const int bid = blockIdx.x;
  const int qt = bid % 5;
  const int h  = (bid / 5) % NH;
  const int b  = bid / (5 * NH);
  const size_t base = (size_t)b * NSEQ * 2304 + h * 64;

  { // stage Q (64 x 64)
    const int r = t >> 3, seg = t & 7;
    #pragma unroll
    for (int i = 0; i < 2; ++i){
      const int r2 = r + 32 * i;
      const unsigned short* src = qkv + base + (size_t)(qt * 64 + r2) * 2304 + seg * 8;
      *(uint4*)&Qs[r2 * 72 + seg * 8] = *(const uint4*)src;
    }
  }
  __syncthreads();
  const int qr = 16 * w + (l & 15);
  const v8s aq0 = *(const v8s*)&Qs[qr * 72 + ((l >> 4) << 3)];
  const v8s aq1 = *(const v8s*)&Qs[qr * 72 + 32 + ((l >> 4) << 3)];

  v4f sacc[20] = {};
  for (int kt = 0; kt < 5; ++kt){
    __syncthreads();
    { // stage K tile
      const int r = t >> 3, seg = t & 7;
      #pragma unroll
      for (int i = 0; i < 2; ++i){
        const int r2 = r + 32 * i;
        const unsigned short* src = qkv + base + 768 + (size_t)(kt * 64 + r2) * 2304 + seg * 8;
        *(uint4*)&KV[r2 * 72 + seg * 8] = *(const uint4*)src;
      }
    }
    __syncthreads();
    #pragma unroll
    for (int f = 0; f < 4; ++f){
      const int kr = 16 * f + (l & 15);
      const v8s b0 = *(const v8s*)&KV[kr * 72 + ((l >> 4) << 3)];
      const v8s b1 = *(const v8s*)&KV[kr * 72 + 32 + ((l >> 4) << 3)];
      sacc[kt * 4 + f] = __builtin_amdgcn_mfma_f32_16x16x32_bf16(aq0, b0, sacc[kt * 4 + f], 0, 0, 0);
      sacc[kt * 4 + f] = __builtin_amdgcn_mfma_f32_16x16x32_bf16(aq1, b1, sacc[kt * 4 + f], 0, 0, 0);
    }
  }

  // wave-parallel softmax; rows live in 16-lane groups
  const float scale = 0.125f;
  #pragma unroll
  for (int r = 0; r < 4; ++r){
    float m = -1e30f;
    #pragma unroll
    for (int f = 0; f < 20; ++f) m = fmaxf(m, sacc[f][r]);
    #pragma unroll
    for (int d = 1; d < 16; d <<= 1) m = fmaxf(m, __shfl_xor(m, d, 64));
    const float Ms = m * scale;
    float sum = 0.f;
    #pragma unroll
    for (int f = 0; f < 20; ++f){ float p = expf(sacc[f][r] * scale - Ms); sacc[f][r] = p; sum += p; }
    #pragma unroll
    for (int d = 1; d < 16; d <<= 1) sum += __shfl_xor(sum, d, 64);
    const float inv = 1.0f / sum;
    const int rowq = 16 * w + ((l >> 4) << 2) + r;
    #pragma unroll
    for (int f = 0; f < 20; ++f)
      Ps[rowq * 328 + f * 16 + (l & 15)] = f2b(sacc[f][r] * inv);
    if (qt == 0){
      #pragma unroll
      for (int f = 4; f < 20; ++f)
        wparts[(((size_t)b * NH + h) * 64 + rowq) * 256 + (f - 4) * 16 + (l & 15)] = sacc[f][r] * inv;
    }
  }

  // P @ V
  v4f cacc[4] = {};
  for (int kt = 0; kt < 5; ++kt){
    __syncthreads();
    { // stage V^T tile: KV[d*72 + m] = V[m][d]
      const int m = t & 31, d0 = (t >> 5) * 8;
      #pragma unroll
      for (int i = 0; i < 2; ++i){
        const int m2 = m + 32 * i;
        const unsigned short* src = qkv + base + 1536 + (size_t)(kt * 64 + m2) * 2304 + d0;
        uint4 dv = *(const uint4*)src;
        const unsigned short* e = (const unsigned short*)&dv;
        #pragma unroll
        for (int jj = 0; jj < 8; ++jj) KV[(d0 + jj) * 72 + m2] = e[jj];
      }
    }
    __syncthreads();
    const int pr = 16 * w + (l & 15);
    const v8s pa0 = *(const v8s*)&Ps[pr * 328 + kt * 64 + ((l >> 4) << 3)];
    const v8s pa1 = *(const v8s*)&Ps[pr * 328 + kt * 64 + 32 + ((l >> 4) << 3)];
    #pragma unroll
    for (int f = 0; f < 4; ++f){
      const int vc = 16 * f + (l & 15);
      const v8s bv0 = *(const v8s*)&KV[vc * 72 + ((l >> 4) << 3)];
      const v8s bv1 = *(const v8s*)&KV[vc * 72 + 32 + ((l >> 4) << 3)];
      cacc[f] = __builtin_amdgcn_mfma_f32_16x16x32_bf16(pa0, bv0, cacc[f], 0, 0, 0);
      cacc[f] = __builtin_amdgcn_mfma_f32_16x16x32_bf16(pa1, bv1, cacc[f], 0, 0, 0);
    }
  }
  #pragma unroll
  for (int f = 0; f < 4; ++f)
    #pragma unroll
    for (int rr = 0; rr < 4; ++rr){
      const int rowq = 16 * w + ((l >> 4) << 2) + rr;
      const int col = 16 * f + (l & 15);
      ctx[(size_t)(b * NSEQ + qt * 64 + rowq) * CDIM + h * 64 + col] = f2b(cacc[f][rr]);
    }
}

// ---------------- w_ts: sum over heads /H then softmax over 256; bf16 x2 ------
__global__ __launch_bounds__(256)
void wts_softmax(const float* __restrict__ wparts,
                 unsigned short* __restrict__ wtsb,
                 unsigned short* __restrict__ wtsbT){
  const int row = blockIdx.x;            // b*64 + n
  const int b = row >> 6, n = row & 63;
  const int j = threadIdx.x;
  const int w = j >> 6, l = j & 63;
  float s = 0.f;
  #pragma unroll
  for (int hh = 0; hh < NH; ++hh)
    s += wparts[(((size_t)b * NH + hh) * 64 + n) * 256 + j];
  s *= (1.0f / NH);
  __shared__ float red[8];
  float m = s;
  #pragma unroll
  for (int d = 1; d < 64; d <<= 1) m = fmaxf(m, __shfl_xor(m, d, 64));
  if (l == 0) red[w] = m;
  __syncthreads();
  m = fmaxf(fmaxf(red[0], red[1]), fmaxf(red[2], red[3]));
  const float e = expf(s - m);
  float sm = e;
  #pragma unroll
  for (int d = 1; d < 64; d <<= 1) sm += __shfl_xor(sm, d, 64);
  if (l == 0) red[4 + w] = sm;
  __syncthreads();
  const float tot = red[4] + red[5] + red[6] + red[7];
  const unsigned short p = f2b(e / tot);
  wtsb [((size_t)b * 64 + n) * 256 + j] = p;
  wtsbT[((size_t)b * 256 + j) * 64 + n] = p;
}

// ---------------- support transpose: (b,320,768) -> (b,768,320) bf16 ----------
__global__ __launch_bounds__(256)
void transT(const unsigned short* __restrict__ in, unsigned short* __restrict__ out){
  __shared__ unsigned short tile[64][65];   // [c][n]
  const int c0 = blockIdx.x * 64, n0 = blockIdx.y * 64, b = blockIdx.z;
  const int tx = threadIdx.x & 31, ty = threadIdx.x >> 5;
  const unsigned short* ib = in + (size_t)b * NSEQ * CDIM;
  unsigned short* ob = out + (size_t)b * CDIM * NSEQ;
  #pragma unroll
  for (int i = 0; i < 64; i += 8){
    const unsigned int v = *(const unsigned int*)&ib[(size_t)(n0 + ty + i) * CDIM + c0 + tx * 2];
    tile[tx * 2][ty + i]     = (unsigned short)(v & 0xffff);
    tile[tx * 2 + 1][ty + i] = (unsigned short)(v >> 16);
  }
  __syncthreads();
  #pragma unroll
  for (int i = 0; i < 64; i += 8){
    const int c = ty + i;
    const unsigned int v = (unsigned int)tile[c][tx * 2] | ((unsigned int)tile[c][tx * 2 + 1] << 16);
    *(unsigned int*)&ob[(size_t)(c0 + c) * NSEQ + n0 + tx * 2] = v;
  }
}

// ---------------- graph matmul via MFMA ---------------------------------------
template<int KC, int SH2>   // KC = K-chunk, SH2 = log2(KC*2)
__global__ __launch_bounds__(256, 2)
void graph_gemm(const unsigned short* __restrict__ A, int KTOT,
                const unsigned short* __restrict__ supT, int koff,
                float* __restrict__ y, int rowoff){
  __shared__ __align__(16) unsigned short As[64 * KC];
  __shared__ __align__(16) unsigned short Bs[128 * KC];
  const int t = threadIdx.x, w = t >> 6, l = t & 63;
  const int mt = blockIdx.x, ct = blockIdx.y, b = blockIdx.z;
  const char* Ab = (const char*)(A + (size_t)b * 16384 + (size_t)mt * 64 * KTOT);
  const char* Bb = (const char*)(supT + (size_t)b * CDIM * NSEQ);
  v4f acc[4][2] = {};

  const int nch = KTOT / KC;
  for (int ch = 0; ch < nch; ++ch){
    if (ch) __syncthreads();
    const int kbase = (koff + ch * KC) * 2;
    #pragma unroll
    for (int i = 0; i < KC / 32; ++i){
      const int gi = w * (KC / 32) + i;
      const int X = gi * 1024 + l * 16;
      const int c = X >> SH2;
      const int k2 = (X & (KC * 2 - 1)) ^ ((c & 7) << 4);
      glds16((const unsigned short*)(Ab + (size_t)c * (KTOT * 2) + ch * KC * 2 + k2),
             As + (gi * 512));
    }
    #pragma unroll
    for (int i = 0; i < KC / 16; ++i){
      const int gi = w * (KC / 16) + i;
      const int X = gi * 1024 + l * 16;
      const int c = X >> SH2;
      const int k2 = (X & (KC * 2 - 1)) ^ ((c & 7) << 4);
      glds16((const unsigned short*)(Bb + (size_t)(ct * 128 + c) * (NSEQ * 2) + kbase + k2),
             Bs + (gi * 512));
    }
    __syncthreads();
    #pragma unroll
    for (int ks = 0; ks < KC / 32; ++ks){
      const int kbyte = ks * 64 + ((l >> 4) << 4);
      v8s af[4], bf2[2];
      #pragma unroll
      for (int mi = 0; mi < 4; ++mi){
        const int r = mi * 16 + (l & 15);
        af[mi] = *(const v8s*)((const char*)As + (r << SH2) + (kbyte ^ ((r & 7) << 4)));
      }
      #pragma unroll
      for (int ni = 0; ni < 2; ++ni){
        const int rb = w * 32 + ni * 16 + (l & 15);
        bf2[ni] = *(const v8s*)((const char*)Bs + (rb << SH2) + (kbyte ^ ((rb & 7) << 4)));
      }
      #pragma unroll
      for (int mi = 0; mi < 4; ++mi)
        #pragma unroll
        for (int ni = 0; ni < 2; ++ni)
          acc[mi][ni] = __builtin_amdgcn_mfma_f32_16x16x32_bf16(af[mi], bf2[ni], acc[mi][ni], 0, 0, 0);
    }
  }

  const int r0 = rowoff + mt * 64 + ((l >> 4) << 2);
  const int c0 = ct * 128 + w * 32 + (l & 15);
  #pragma unroll
  for (int mi = 0; mi < 4; ++mi)
    #pragma unroll
    for (int ni = 0; ni < 2; ++ni)
      #pragma unroll
      for (int rr = 0; rr < 4; ++rr)
        y[((size_t)b * NSEQ + r0 + mi * 16 + rr) * CDIM + c0 + ni * 16] = acc[mi][ni][rr];
}

// ---------------- final: out = y + LN(y) --------------------------------------
__global__ __launch_bounds__(192)
void ln_final(const float* __restrict__ y, const float* __restrict__ g3,
              const float* __restrict__ b3, float* __restrict__ out){
  const int row = blockIdx.x;
  const int t = threadIdx.x, w = t >> 6, l = t & 63;
  const float4 v = *(const float4*)(y + (size_t)row * CDIM + t * 4);
  float s  = v.x + v.y + v.z + v.w;
  float s2 = v.x*v.x + v.y*v.y + v.z*v.z + v.w*v.w;
  __shared__ float r1[3], r2[3];
  #pragma unroll
  for (int d = 1; d < 64; d <<= 1){ s += __shfl_xor(s, d, 64); s2 += __shfl_xor(s2, d, 64); }
  if (l == 0){ r1[w] = s; r2[w] = s2; }
  __syncthreads();
  const float S = r1[0] + r1[1] + r1[2];
  const float S2 = r2[0] + r2[1] + r2[2];
  const float mean = S * (1.0f / CDIM);
  const float var  = S2 * (1.0f / CDIM) - mean * mean;
  const float rs = rsqrtf(var + 1e-5f);
  const float4 gg = *(const float4*)(g3 + t * 4);
  const float4 bb = *(const float4*)(b3 + t * 4);
  float4 o;
  o.x = v.x + (v.x - mean) * rs * gg.x + bb.x;
  o.y = v.y + (v.y - mean) * rs * gg.y + bb.y;
  o.z = v.z + (v.z - mean) * rs * gg.z + bb.z;
  o.w = v.w + (v.w - mean) * rs * gg.w + bb.w;
  *(float4*)(out + (size_t)row * CDIM + t * 4) = o;
}

extern "C" void kernel_launch(void* const* d_in, const int* in_sizes, int n_in,
                              void* d_out, int out_size, void* d_ws, size_t ws_size,
                              hipStream_t stream){
  (void)in_sizes; (void)n_in; (void)out_size; (void)ws_size;
  const float* x    = (const float*)d_in[0];
  const float* g1   = (const float*)d_in[3];
  const float* b1   = (const float*)d_in[4];
  const float* Wqkv = (const float*)d_in[5];
  const float* Wproj= (const float*)d_in[6];
  const float* bproj= (const float*)d_in[7];
  const float* g2   = (const float*)d_in[8];
  const float* b2   = (const float*)d_in[9];
  const float* W1   = (const float*)d_in[10];
  const float* bm1  = (const float*)d_in[11];
  const float* W2   = (const float*)d_in[12];
  const float* bm2  = (const float*)d_in[13];
  const float* Wg   = (const float*)d_in[14];
  const float* bg   = (const float*)d_in[15];
  const float* g3   = (const float*)d_in[16];
  const float* b3   = (const float*)d_in[17];
  float* out = (float*)d_out;
  char* ws = (char*)d_ws;

  // workspace layout (bytes); aliases are time-disjoint
  unsigned short* wqkvT = (unsigned short*)(ws + 0);          // 3,538,944
  unsigned short* wprojT= (unsigned short*)(ws + 3538944);    // 1,179,648
  unsigned short* w1T   = (unsigned short*)(ws + 4718592);    // 4,718,592
  unsigned short* w2T   = (unsigned short*)(ws + 9437184);    // 4,718,592
  unsigned short* wgT   = (unsigned short*)(ws + 14155776);   // 1,179,648
  unsigned short* xn1   = (unsigned short*)(ws + 15335424);   // 15,728,640
  unsigned short* qkvb  = (unsigned short*)(ws + 31064064);   // 47,185,920
  unsigned short* hb    = (unsigned short*)(ws + 15335424);   // aliases xn1+qkv
  unsigned short* supT  = (unsigned short*)(ws + 15335424);   // aliases hb (dead after MLP2)
  unsigned short* ctxb  = (unsigned short*)(ws + 78249984);   // 15,728,640
  unsigned short* x2b   = (unsigned short*)(ws + 78249984);   // aliases ctx
  unsigned short* xn2   = (unsigned short*)(ws + 93978624);   // 15,728,640
  unsigned short* supb  = (unsigned short*)(ws + 93978624);   // aliases xn2
  float*          x1    = (float*)(ws + 109707264);           // 31,457,280
  float*          wparts= (float*)(ws + 109707264);           // aliases x1
  float*          yb    = (float*)(ws + 109707264);           // aliases x1 (dead after MLP2)
  unsigned short* wtsb  = (unsigned short*)(ws + 141164544);  // 1,048,576
  unsigned short* wtsbT = (unsigned short*)(ws + 142213120);  // 1,048,576

  // 1) all weights -> bf16 transposed, one dispatch
  castAll<<<7488, 256, 0, stream>>>(Wqkv, Wproj, W1, W2, Wg,
                                    wqkvT, wprojT, w1T, w2T, wgT);

  // 2) LN1 -> bf16
  ln_to_bf16<<<MROWS, 192, 0, stream>>>(x, g1, b1, xn1);

  // 3) QKV GEMM (no bias): M=10240, N=2304, K=768
  gemm_cv<false,false,false,true,false><<<dim3(80, 18), 256, 0, stream>>>(
      xn1, wqkvT, 2304, CDIM, nullptr, nullptr, qkvb, nullptr);

  // 4) attention (also emits per-head prob slices for w_ts)
  attn_kernel<<<NB * NH * 5, 256, 0, stream>>>(qkvb, ctxb, wparts);

  // 5) w_ts = softmax(sum_h attn[:,:64,64:]/H), bf16 in both orientations
  //    (must run before proj: wparts aliases x1)
  wts_softmax<<<NB * 64, 256, 0, stream>>>(wparts, wtsb, wtsbT);

  // 6) proj + bias + residual(x) -> x1 (f32)
  gemm_cv<true,true,false,false,true><<<dim3(80, 6), 256, 0, stream>>>(
      ctxb, wprojT, CDIM, CDIM, bproj, x, nullptr, x1);

  // 7) LN2 -> bf16
  ln_to_bf16<<<MROWS, 192, 0, stream>>>(x1, g2, b2, xn2);

  // 8) MLP1 + bias + exact GELU -> h (bf16): N=3072, K=768
  gemm_cv<true,false,true,true,false><<<dim3(80, 24), 256, 0, stream>>>(
      xn2, w1T, MLPH, CDIM, bm1, nullptr, hb, nullptr);

  // 9) MLP2 + bias + residual(x1) -> x2 (bf16): N=768, K=3072
  gemm_cv<true,true,false,true,false><<<dim3(80, 6), 256, 0, stream>>>(
      hb, w2T, CDIM, MLPH, bm2, x1, x2b, nullptr);

  // 10) support = x2 @ Wg + bg (bf16)
  gemm_cv<true,false,false,true,false><<<dim3(80, 6), 256, 0, stream>>>(
      x2b, wgT, CDIM, CDIM, bg, nullptr, supb, nullptr);

  // 11) supT = transpose(support) per batch
  transT<<<dim3(CDIM/64, NSEQ/64, NB), 256, 0, stream>>>(supb, supT);

  // 12) y = adj @ support via two batched MFMA GEMMs
  graph_gemm<128, 8><<<dim3(1, 6, NB), 256, 0, stream>>>(wtsb, 256, supT, 64, yb, 0);
  graph_gemm<64, 7><<<dim3(4, 6, NB), 256, 0, stream>>>(wtsbT, 64, supT, 0, yb, 64);

  // 13) out = y + LN(y)
  ln_final<<<MROWS, 192, 0, stream>>>(yb, g3, b3, out);
}